// Round 13
// baseline (257.241 us; speedup 1.0000x reference)
//
#include <hip/hip_runtime.h>
#include <hip/hip_bf16.h>
#include <math.h>

typedef __hip_bfloat16 bf16;

// ---------------- problem constants ----------------
#define LSEQ 4096
#define DI 128
#define NSTATE 16
#define NK 4
#define NCHUNK 256
#define CLEN 16
#define CHTOT 16384   // 2 scans * 4 k * 128 d * 16 n

// ---------------- workspace layout ----------------
#define OFF_XC0  0
#define OFF_XC1  (OFF_XC0 + DI*LSEQ)
#define OFF_XT0  (OFF_XC1 + DI*LSEQ)
#define OFF_XT1  (OFF_XT0 + DI*LSEQ)
#define OFF_SZP0 (OFF_XT1 + DI*LSEQ)        // silu(z), PLANE layout [d][l]
#define OFF_SZP1 (OFF_SZP0 + DI*LSEQ)
#define OFF_CHP  (OFF_SZP1 + DI*LSEQ)       // [chunk][chain]; after comb = h-init
#define OFF_CHS  (OFF_CHP + NCHUNK*CHTOT)
#define OFF_OY   (OFF_CHS + NCHUNK*CHTOT)   // [s][k][l][d]
#define WS_FLOATS (OFF_OY + 2*NK*LSEQ*DI)

// scan smem (floats, per half): x0t 2176 + us 2176 + dtr 64 + Bt 320 (+ Ct 320)
#define SA_HALF 4736
#define SB_HALF 5056

__device__ __forceinline__ float softplus_f(float x) {
  return x > 20.f ? x : __logf(1.f + __expf(x));
}
__device__ __forceinline__ float silu_f(float x) {
  return x / (1.f + __expf(-x));
}
__device__ __forceinline__ float cvt(float v) { return v; }
__device__ __forceinline__ float cvt(bf16 v) { return __bfloat162float(v); }

// dtype probe: even bf16 halves of an fp32 buffer have random exponents
__device__ __forceinline__ int probe_f32(const void* probe, int t, int* sh) {
  if (t < 64) {
    int idx = 2 * ((t * 127) & 4095);
    float v = __bfloat162float(((const bf16*)probe)[idx]);
    int weird = (!(v == v)) || (fabsf(v) > 4.0f);
    unsigned long long m = __ballot(weird);
    if (t == 0) *sh = (__popcll(m) >= 8) ? 1 : 0;
  }
  __syncthreads();
  return *sh;
}

// ================= phase bodies (compile-time dtype T) =================

// k_front: block (b,d). xi-row dot + z-row dot over all 4096 px, conv own plane,
// emit xc[d][l], xT[d][l] and silu(z) -> SZP[d][l].
template <typename T>
__device__ __forceinline__ void ph_front(const void* x0, const void* x1, const void* w0,
                                         const void* w1, const void* cw0, const void* cb0,
                                         const void* cw1, const void* cb1,
                                         float* __restrict__ ws, float* sm, int t, int unit) {
  int b = unit >> 7, d = unit & 127;
  const T* __restrict__ x = (const T*)(b ? x1 : x0);
  const T* __restrict__ w = (const T*)(b ? w1 : w0);
  const T* cw = (const T*)(b ? cw1 : cw0);
  float bias = cvt(((const T*)(b ? cb1 : cb0))[d]);
  float* xc = ws + (b ? OFF_XC1 : OFF_XC0) + d * LSEQ;
  float* xt = ws + (b ? OFF_XT1 : OFF_XT0) + d * LSEQ;
  float* szp = ws + (b ? OFF_SZP1 : OFF_SZP0) + d * LSEQ;
  float* wsm = sm;          // [128]: w_xi 0..63, w_z 64..127
  float* pl = sm + 128;     // xi plane [64][64]
  float* po = sm + 4224;    // conv out transposed [64][65]
  if (t < 64) wsm[t] = cvt(w[d * 64 + t]);
  else if (t < 128) wsm[t] = cvt(w[(128 + d) * 64 + (t - 64)]);
  __syncthreads();
  float wxi[64], wz[64];
#pragma unroll
  for (int c = 0; c < 64; c++) {
    wxi[c] = wsm[c];
    wz[c] = wsm[64 + c];
  }
  float wreg[9];
#pragma unroll
  for (int i = 0; i < 9; i++) wreg[i] = cvt(cw[d * 9 + i]);
#pragma unroll 2
  for (int it = 0; it < 16; it++) {
    int l = t + 256 * it;
    const T* xr = x + l * 64;
    float axi = 0.f, az = 0.f;
#pragma unroll
    for (int c = 0; c < 64; c++) {
      float xv = cvt(xr[c]);
      axi += xv * wxi[c];
      az += xv * wz[c];
    }
    pl[l] = axi;
    szp[l] = silu_f(az);  // coalesced (lanes = consecutive l)
  }
  __syncthreads();
  for (int i = t; i < 4096; i += 256) {
    int h = i >> 6, w2 = i & 63;
    float a = bias;
#pragma unroll
    for (int kh = 0; kh < 3; kh++) {
      int hh = h + kh - 1;
      if (hh < 0 || hh > 63) continue;
#pragma unroll
      for (int kw = 0; kw < 3; kw++) {
        int ww = w2 + kw - 1;
        if (ww < 0 || ww > 63) continue;
        a += pl[hh * 64 + ww] * wreg[kh * 3 + kw];
      }
    }
    float r = silu_f(a);
    xc[i] = r;
    po[w2 * 65 + h] = r;
  }
  __syncthreads();
  for (int i = t; i < 4096; i += 256) xt[i] = po[(i >> 6) * 65 + (i & 63)];
}

// local x_dbl rows [0,NC): writes dtr (c<4), Bt (4..19), Ct (20..35)
template <typename T, int NC>
__device__ __forceinline__ void local_xdbl(const T* __restrict__ xpw, int k, int rev,
                                           const float* x0t, float* dtr, float* Bt,
                                           float* Ct, int t) {
  for (int i = t & 127; i < NC * 16; i += 128) {
    int c = i >> 4, lj = i & 15;
    int col = rev ? 15 - lj : lj;
    const T* wrow = xpw + k * 4608 + c * 128;
    float a = 0.f;
#pragma unroll 8
    for (int dd = 0; dd < 128; dd++) a += x0t[dd * 17 + col] * cvt(wrow[dd]);
    if (c < 4) dtr[c * 16 + lj] = a;
    else if (c < 20) Bt[lj * 20 + (c - 4)] = a;
    else Ct[lj * 20 + (c - 20)] = a;
  }
}

// cross-wiring: s=0 uses dt1/A1; s=1 uses dt0/A0. Fast path: A[n]=(n+1)A[0].
template <typename T>
__device__ __forceinline__ void ph_scanA(const void* xpw0, const void* al0, const void* al1,
                                         const void* dtw0, const void* dtw1, const void* dtb0,
                                         const void* dtb1, float* __restrict__ ws, float* sm,
                                         int t, int gc) {
  int half = t >> 7, d = t & 127;
  int s = gc >> 10, k = (gc >> 8) & 3, c = gc & 255;
  float* base = sm + half * SA_HALF;
  float* x0t = base;          // branch-0 tile [128][17]
  float* us = base + 2176;    // u tile (s=1 only; s=0 aliases x0t)
  float* dtr = base + 4352;   // [4][16]
  float* Bt = base + 4416;    // 16 rows stride 20
  const T* alog = (const T*)(s ? al0 : al1);
  const T* dtw = (const T*)(s ? dtw0 : dtw1);
  const T* dtb = (const T*)(s ? dtb0 : dtb1);
  int rev = (k >= 2);
  int l0 = c * CLEN;
  int mb = rev ? (4080 - l0) : l0;
  const float* p0 = ws + OFF_XC0 + ((k & 1) ? 2 * DI * LSEQ : 0);  // branch-0 plane
  for (int i = d; i < 2048; i += 128) {
    int d2 = i >> 4, c2 = i & 15;
    x0t[d2 * 17 + c2] = p0[d2 * LSEQ + mb + c2];
  }
  const float* uld;
  if (s == 0) {
    uld = x0t;
  } else {
    const float* p1 = ws + OFF_XC1 + ((k & 1) ? 2 * DI * LSEQ : 0);
    for (int i = d; i < 2048; i += 128) {
      int d2 = i >> 4, c2 = i & 15;
      us[d2 * 17 + c2] = p1[d2 * LSEQ + mb + c2];
    }
    uld = us;
  }
  float A[NSTATE];
#pragma unroll
  for (int n = 0; n < NSTATE; n++) A[n] = -__expf(cvt(alog[(k * DI + d) * NSTATE + n]));
  bool fastp = true;
#pragma unroll
  for (int n = 1; n < NSTATE; n++)
    fastp = fastp && (fabsf(A[n] - (float)(n + 1) * A[0]) <= 1e-3f * fabsf(A[n]));
  float w0 = cvt(dtw[(k * DI + d) * 4 + 0]), w1 = cvt(dtw[(k * DI + d) * 4 + 1]);
  float w2 = cvt(dtw[(k * DI + d) * 4 + 2]), w3 = cvt(dtw[(k * DI + d) * 4 + 3]);
  float dbias = cvt(dtb[k * DI + d]);
  __syncthreads();
  local_xdbl<T, 20>((const T*)xpw0, k, rev, x0t, dtr, Bt, nullptr, t);
  float h[NSTATE];
#pragma unroll
  for (int n = 0; n < NSTATE; n++) h[n] = 0.f;
  float sde = 0.f;
  __syncthreads();
  float de[16];
#pragma unroll
  for (int j = 0; j < 16; j++) {
    de[j] = softplus_f(dtr[j] * w0 + dtr[16 + j] * w1 + dtr[32 + j] * w2 + dtr[48 + j] * w3 +
                       dbias);
    sde += de[j];
  }
#pragma unroll
  for (int j = 0; j < 16; j++) {
    float u = uld[d * 17 + (rev ? 15 - j : j)];
    float duj = de[j] * u;
    float4 b0 = *(const float4*)&Bt[j * 20 + 0];
    float4 b1 = *(const float4*)&Bt[j * 20 + 4];
    float4 b2 = *(const float4*)&Bt[j * 20 + 8];
    float4 b3 = *(const float4*)&Bt[j * 20 + 12];
    float bv[16] = {b0.x, b0.y, b0.z, b0.w, b1.x, b1.y, b1.z, b1.w,
                    b2.x, b2.y, b2.z, b2.w, b3.x, b3.y, b3.z, b3.w};
    if (fastp) {
      float e1 = __expf(de[j] * A[0]);
      float p = e1;
#pragma unroll
      for (int n = 0; n < NSTATE; n++) {
        h[n] = p * h[n] + duj * bv[n];
        p *= e1;
      }
    } else {
#pragma unroll
      for (int n = 0; n < NSTATE; n++) {
        float da = __expf(de[j] * A[n]);
        h[n] = da * h[n] + duj * bv[n];
      }
    }
  }
  int chainb = ((s * 4 + k) * DI + d) * NSTATE;
  float* Pp = ws + OFF_CHP + c * CHTOT + chainb;
  float* Sp = ws + OFF_CHS + c * CHTOT + chainb;
#pragma unroll
  for (int q = 0; q < 4; q++) {
    ((float4*)Pp)[q] = make_float4(__expf(A[4 * q] * sde), __expf(A[4 * q + 1] * sde),
                                   __expf(A[4 * q + 2] * sde), __expf(A[4 * q + 3] * sde));
    ((float4*)Sp)[q] = make_float4(h[4 * q], h[4 * q + 1], h[4 * q + 2], h[4 * q + 3]);
  }
}

template <typename T>
__device__ __forceinline__ void ph_scanB(const void* xpw0, const void* al0, const void* al1,
                                         const void* dtw0, const void* dtw1, const void* dtb0,
                                         const void* dtb1, const void* ds0, const void* ds1,
                                         float* __restrict__ ws, float* sm, int t, int gc) {
  int half = t >> 7, d = t & 127;
  int s = gc >> 10, k = (gc >> 8) & 3, c = gc & 255;
  float* base = sm + half * SB_HALF;
  float* x0t = base;
  float* us = base + 2176;
  float* dtr = base + 4352;
  float* Bt = base + 4416;
  float* Ct = base + 4736;
  const T* alog = (const T*)(s ? al0 : al1);
  const T* dtw = (const T*)(s ? dtw0 : dtw1);
  const T* dtb = (const T*)(s ? dtb0 : dtb1);
  const T* Dvec = (const T*)(s ? ds0 : ds1);
  float* oyb = ws + OFF_OY + (s * NK + k) * (LSEQ * DI);
  int rev = (k >= 2);
  int l0 = c * CLEN;
  int mb = rev ? (4080 - l0) : l0;
  const float* p0 = ws + OFF_XC0 + ((k & 1) ? 2 * DI * LSEQ : 0);
  for (int i = d; i < 2048; i += 128) {
    int d2 = i >> 4, c2 = i & 15;
    x0t[d2 * 17 + c2] = p0[d2 * LSEQ + mb + c2];
  }
  const float* uld;
  if (s == 0) {
    uld = x0t;
  } else {
    const float* p1 = ws + OFF_XC1 + ((k & 1) ? 2 * DI * LSEQ : 0);
    for (int i = d; i < 2048; i += 128) {
      int d2 = i >> 4, c2 = i & 15;
      us[d2 * 17 + c2] = p1[d2 * LSEQ + mb + c2];
    }
    uld = us;
  }
  float A[NSTATE];
#pragma unroll
  for (int n = 0; n < NSTATE; n++) A[n] = -__expf(cvt(alog[(k * DI + d) * NSTATE + n]));
  bool fastp = true;
#pragma unroll
  for (int n = 1; n < NSTATE; n++)
    fastp = fastp && (fabsf(A[n] - (float)(n + 1) * A[0]) <= 1e-3f * fabsf(A[n]));
  float w0 = cvt(dtw[(k * DI + d) * 4 + 0]), w1 = cvt(dtw[(k * DI + d) * 4 + 1]);
  float w2 = cvt(dtw[(k * DI + d) * 4 + 2]), w3 = cvt(dtw[(k * DI + d) * 4 + 3]);
  float dbias = cvt(dtb[k * DI + d]);
  float Dv = cvt(Dvec[k * DI + d]);
  int chainb = ((s * 4 + k) * DI + d) * NSTATE;
  const float* Hp = ws + OFF_CHP + c * CHTOT + chainb;
  float h[NSTATE];
#pragma unroll
  for (int q = 0; q < 4; q++) {
    float4 hv = ((const float4*)Hp)[q];
    h[4 * q] = hv.x; h[4 * q + 1] = hv.y; h[4 * q + 2] = hv.z; h[4 * q + 3] = hv.w;
  }
  __syncthreads();
  local_xdbl<T, 36>((const T*)xpw0, k, rev, x0t, dtr, Bt, Ct, t);
  __syncthreads();
  float de[16];
#pragma unroll
  for (int j = 0; j < 16; j++) {
    de[j] = softplus_f(dtr[j] * w0 + dtr[16 + j] * w1 + dtr[32 + j] * w2 + dtr[48 + j] * w3 +
                       dbias);
  }
#pragma unroll
  for (int j = 0; j < 16; j++) {
    float u = uld[d * 17 + (rev ? 15 - j : j)];
    float duj = de[j] * u;
    float4 b0 = *(const float4*)&Bt[j * 20 + 0];
    float4 b1 = *(const float4*)&Bt[j * 20 + 4];
    float4 b2 = *(const float4*)&Bt[j * 20 + 8];
    float4 b3 = *(const float4*)&Bt[j * 20 + 12];
    float bv[16] = {b0.x, b0.y, b0.z, b0.w, b1.x, b1.y, b1.z, b1.w,
                    b2.x, b2.y, b2.z, b2.w, b3.x, b3.y, b3.z, b3.w};
    float4 c0 = *(const float4*)&Ct[j * 20 + 0];
    float4 c1 = *(const float4*)&Ct[j * 20 + 4];
    float4 c2 = *(const float4*)&Ct[j * 20 + 8];
    float4 c3 = *(const float4*)&Ct[j * 20 + 12];
    float cv[16] = {c0.x, c0.y, c0.z, c0.w, c1.x, c1.y, c1.z, c1.w,
                    c2.x, c2.y, c2.z, c2.w, c3.x, c3.y, c3.z, c3.w};
    float y = 0.f;
    if (fastp) {
      float e1 = __expf(de[j] * A[0]);
      float p = e1;
#pragma unroll
      for (int n = 0; n < NSTATE; n++) {
        h[n] = p * h[n] + duj * bv[n];
        y += h[n] * cv[n];
        p *= e1;
      }
    } else {
#pragma unroll
      for (int n = 0; n < NSTATE; n++) {
        float da = __expf(de[j] * A[n]);
        h[n] = da * h[n] + duj * bv[n];
        y += h[n] * cv[n];
      }
    }
    y += u * Dv;
    oyb[(l0 + j) * DI + d] = y;
  }
}

template <typename T>
__device__ __forceinline__ void ph_post(const void* g0_, const void* be0_, const void* g1_,
                                        const void* be1_, const void* wo0, const void* wo1,
                                        const float* __restrict__ ws, float* sm, int t,
                                        int unit, int f32, void* __restrict__ out) {
  int b = unit >> 8;
  int l0 = (unit & 255) * 16;
  const float* oy = ws + OFF_OY + b * (NK * LSEQ * DI);
  const float* szp = ws + (b ? OFF_SZP1 : OFF_SZP0);
  const T* g = (const T*)(b ? g1_ : g0_);
  const T* be = (const T*)(b ? be1_ : be0_);
  const T* wo = (const T*)(b ? wo1 : wo0);
  float* yl = sm;          // [16][132]
  float* wl = sm + 2112;   // [64][129]
  float* szl = sm + 10368; // [16][132]
  for (int i = t; i < 8192; i += 256) wl[(i >> 7) * 129 + (i & 127)] = cvt(wo[i]);
  for (int i = t; i < 2048; i += 256) {
    int dd = i >> 4, lj = i & 15;
    szl[lj * 132 + dd] = szp[dd * LSEQ + l0 + lj];
  }
  __syncthreads();
  int wv = t >> 6, lane = t & 63;
  float g1 = cvt(g[lane]), g2 = cvt(g[lane + 64]);
  float be1 = cvt(be[lane]), be2 = cvt(be[lane + 64]);
#pragma unroll
  for (int i = 0; i < 4; i++) {
    int r = wv + 4 * i;
    int l = l0 + r;
    int lt = ((l & 63) << 6) | (l >> 6);
    float v1 = oy[(0 * LSEQ + l) * DI + lane] + oy[(1 * LSEQ + lt) * DI + lane] +
               oy[(2 * LSEQ + (4095 - l)) * DI + lane] +
               oy[(3 * LSEQ + (4095 - lt)) * DI + lane];
    float v2 = oy[(0 * LSEQ + l) * DI + lane + 64] + oy[(1 * LSEQ + lt) * DI + lane + 64] +
               oy[(2 * LSEQ + (4095 - l)) * DI + lane + 64] +
               oy[(3 * LSEQ + (4095 - lt)) * DI + lane + 64];
    float s1 = v1 + v2, s2 = v1 * v1 + v2 * v2;
#pragma unroll
    for (int m = 1; m < 64; m <<= 1) {
      s1 += __shfl_xor(s1, m);
      s2 += __shfl_xor(s2, m);
    }
    float mean = s1 * (1.f / 128.f);
    float var = s2 * (1.f / 128.f) - mean * mean;
    float inv = rsqrtf(var + 1e-5f);
    yl[r * 132 + lane] = ((v1 - mean) * inv * g1 + be1) * szl[r * 132 + lane];
    yl[r * 132 + lane + 64] = ((v2 - mean) * inv * g2 + be2) * szl[r * 132 + lane + 64];
  }
  __syncthreads();
  int m = t & 63, rg = t >> 6;
  float acc0 = 0.f, acc1 = 0.f, acc2 = 0.f, acc3 = 0.f;
  for (int q = 0; q < 32; q++) {
    float w0 = wl[m * 129 + 4 * q], w1 = wl[m * 129 + 4 * q + 1];
    float w2 = wl[m * 129 + 4 * q + 2], w3 = wl[m * 129 + 4 * q + 3];
    float4 y0 = *(const float4*)&yl[(rg + 0) * 132 + 4 * q];
    float4 y1 = *(const float4*)&yl[(rg + 4) * 132 + 4 * q];
    float4 y2 = *(const float4*)&yl[(rg + 8) * 132 + 4 * q];
    float4 y3 = *(const float4*)&yl[(rg + 12) * 132 + 4 * q];
    acc0 += y0.x * w0 + y0.y * w1 + y0.z * w2 + y0.w * w3;
    acc1 += y1.x * w0 + y1.y * w1 + y1.z * w2 + y1.w * w3;
    acc2 += y2.x * w0 + y2.y * w1 + y2.z * w2 + y2.w * w3;
    acc3 += y3.x * w0 + y3.y * w1 + y3.z * w2 + y3.w * w3;
  }
  float accs[4] = {acc0, acc1, acc2, acc3};
#pragma unroll
  for (int i = 0; i < 4; i++) {
    int l = l0 + rg + 4 * i;
    int oi = b * (LSEQ * 64) + l * 64 + m;
    if (f32) ((float*)out)[oi] = accs[i];
    else ((bf16*)out)[oi] = __float2bfloat16(accs[i]);
  }
}

// ================= kernels =================

__global__ __launch_bounds__(256) void k_front(const void* x0, const void* x1,
                                               const void* w0, const void* w1,
                                               const void* cw0, const void* cb0,
                                               const void* cw1, const void* cb1,
                                               const void* probe, float* __restrict__ ws) {
  __shared__ __align__(16) float sm[8384];
  __shared__ int sf32;
  int t = threadIdx.x;
  int f32 = probe_f32(probe, t, &sf32);
  if (f32) ph_front<float>(x0, x1, w0, w1, cw0, cb0, cw1, cb1, ws, sm, t, blockIdx.x);
  else ph_front<bf16>(x0, x1, w0, w1, cw0, cb0, cw1, cb1, ws, sm, t, blockIdx.x);
}

__global__ __launch_bounds__(256, 2) void k_scanA(const void* xpw0, const void* al0,
                                                  const void* al1, const void* dtw0,
                                                  const void* dtw1, const void* dtb0,
                                                  const void* dtb1, const void* probe,
                                                  float* __restrict__ ws) {
  __shared__ __align__(16) float sm[2 * SA_HALF];
  __shared__ int sf32;
  int t = threadIdx.x;
  int f32 = probe_f32(probe, t, &sf32);
  int gc = blockIdx.x * 2 + (t >> 7);
  if (f32) ph_scanA<float>(xpw0, al0, al1, dtw0, dtw1, dtb0, dtb1, ws, sm, t, gc);
  else ph_scanA<bf16>(xpw0, al0, al1, dtw0, dtw1, dtb0, dtb1, ws, sm, t, gc);
}

__global__ __launch_bounds__(256) void k_comb(float* __restrict__ ws) {
  int chain = blockIdx.x * 256 + threadIdx.x;
  float* P = ws + OFF_CHP + chain;
  float* S = ws + OFF_CHS + chain;
  float h = 0.f;
  for (int g = 0; g < NCHUNK; g += 8) {
    float p[8], sv[8];
#pragma unroll
    for (int i = 0; i < 8; i++) {
      p[i] = P[(g + i) * CHTOT];
      sv[i] = S[(g + i) * CHTOT];
    }
#pragma unroll
    for (int i = 0; i < 8; i++) {
      P[(g + i) * CHTOT] = h;
      h = p[i] * h + sv[i];
    }
  }
}

__global__ __launch_bounds__(256, 2) void k_scanB(const void* xpw0, const void* al0,
                                                  const void* al1, const void* dtw0,
                                                  const void* dtw1, const void* dtb0,
                                                  const void* dtb1, const void* ds0,
                                                  const void* ds1, const void* probe,
                                                  float* __restrict__ ws) {
  __shared__ __align__(16) float sm[2 * SB_HALF];
  __shared__ int sf32;
  int t = threadIdx.x;
  int f32 = probe_f32(probe, t, &sf32);
  int gc = blockIdx.x * 2 + (t >> 7);
  if (f32) ph_scanB<float>(xpw0, al0, al1, dtw0, dtw1, dtb0, dtb1, ds0, ds1, ws, sm, t, gc);
  else ph_scanB<bf16>(xpw0, al0, al1, dtw0, dtw1, dtb0, dtb1, ds0, ds1, ws, sm, t, gc);
}

__global__ __launch_bounds__(256) void k_post(const void* g0_, const void* be0_,
                                              const void* g1_, const void* be1_,
                                              const void* wo0, const void* wo1,
                                              const void* probe,
                                              const float* __restrict__ ws,
                                              void* __restrict__ out) {
  __shared__ __align__(16) float sm[12480];
  __shared__ int sf32;
  int t = threadIdx.x;
  int f32 = probe_f32(probe, t, &sf32);
  if (f32) ph_post<float>(g0_, be0_, g1_, be1_, wo0, wo1, ws, sm, t, blockIdx.x, f32, out);
  else ph_post<bf16>(g0_, be0_, g1_, be1_, wo0, wo1, ws, sm, t, blockIdx.x, f32, out);
}

extern "C" void kernel_launch(void* const* d_in, const int* in_sizes, int n_in,
                              void* d_out, int out_size, void* d_ws, size_t ws_size,
                              hipStream_t stream) {
  float* ws = (float*)d_ws;
  const void* probe = d_in[2];  // in_proj0_w

  k_front<<<dim3(256), 256, 0, stream>>>(d_in[0], d_in[1], d_in[2], d_in[3], d_in[4],
                                         d_in[5], d_in[6], d_in[7], probe, ws);
  k_scanA<<<dim3(1024), 256, 0, stream>>>(d_in[8], d_in[14], d_in[15], d_in[10], d_in[11],
                                          d_in[12], d_in[13], probe, ws);
  k_comb<<<dim3(64), 256, 0, stream>>>(ws);
  k_scanB<<<dim3(1024), 256, 0, stream>>>(d_in[8], d_in[14], d_in[15], d_in[10], d_in[11],
                                          d_in[12], d_in[13], d_in[16], d_in[17], probe, ws);
  k_post<<<dim3(512), 256, 0, stream>>>(d_in[18], d_in[19], d_in[20], d_in[21],
                                        d_in[22], d_in[23], probe, ws, d_out);
}